// Round 11
// baseline (123.622 us; speedup 1.0000x reference)
//
#include <hip/hip_runtime.h>

// CenterLossForward:
//   loss        = LAMBDA/BATCH * sum_b ||batch_b - centers[y_b]||^2
//   new_centers = centers; new_centers[y_b] += ALPHA*(batch_b - centers[y_b])  (dups accumulate)
// d_out layout: [loss (1 float)] [new_centers (NUM_CLASSES*EMBED floats)]
//
// R11: no runtime fill nodes in the graph (own init kernels; loss via
// per-wave partials + final reduce). Copy: 32B/lane shfl-realign (3 shfl per
// 32B vs 8), plain loads + non-temporal stores (best known config, R6).

constexpr int   NUM_CLASSES = 100000;
constexpr int   EMBED       = 512;
constexpr int   BATCH       = 4096;
constexpr float LAMBDA      = 0.01f;
constexpr float ALPHA       = 0.1f;

constexpr long  NFLOAT = (long)NUM_CLASSES * EMBED;   // 51,200,000
constexpr long  NGRP   = (NFLOAT - 3) / 4;            // 12,799,999 dst float4 groups
constexpr long  NSRC4  = NFLOAT / 4;                  // 12,800,000 src float4 words
constexpr int   NWAVES_UPD = 4096;                    // update grid: 1024 blk * 4 waves

typedef float f4 __attribute__((ext_vector_type(4)));

__global__ void init_head_kernel(int* __restrict__ head) {
    int c = blockIdx.x * blockDim.x + threadIdx.x;
    if (c < NUM_CLASSES) head[c] = -1;
}

__global__ void link_kernel(const int* __restrict__ y, int* __restrict__ head,
                            int* __restrict__ nxt) {
    int s = blockIdx.x * blockDim.x + threadIdx.x;
    if (s < BATCH) nxt[s] = atomicExch(&head[y[s]], s);
}

// Shifted copy, 2 groups (32B) per thread:
//   dst4[1+g] = {src[4g+3] .. src[4g+6]}
//   g0=2p: {s0.w, s1.xyz} local;  g1=2p+1: {s1.w, s2.xyz}, s2 from next lane.
__global__ void __launch_bounds__(256) copy_shift2_kernel(
        const f4* __restrict__ src4, f4* __restrict__ dst4,
        const float* __restrict__ src, float* __restrict__ dst) {
    const int  lane = threadIdx.x & 63;
    const long gw   = (long)((blockIdx.x * blockDim.x + threadIdx.x) >> 6);
    const long nw   = (long)((gridDim.x * blockDim.x) >> 6);
    const long npair = (NGRP + 1) / 2;

    for (long base = gw * 64; base < npair; base += nw * 64) {
        const long p  = base + lane;
        const long g0 = 2 * p;
        const long g1 = g0 + 1;

        f4 s0 = {0.f, 0.f, 0.f, 0.f}, s1 = s0;
        if (g0 < NGRP) { s0 = src4[g0]; s1 = src4[g1]; }  // g1 < NSRC4 guaranteed

        // s2.xyz = next lane's s0.xyz (lane 63: direct load)
        float nx = __shfl_down(s0.x, 1, 64);
        float ny = __shfl_down(s0.y, 1, 64);
        float nz = __shfl_down(s0.z, 1, 64);
        if (lane == 63 && g0 + 2 < NSRC4) {
            f4 s2 = src4[g0 + 2];
            nx = s2.x; ny = s2.y; nz = s2.z;
        }

        if (g0 < NGRP) {
            f4 o0 = {s0.w, s1.x, s1.y, s1.z};
            __builtin_nontemporal_store(o0, &dst4[1 + g0]);
            if (g1 < NGRP) {
                f4 o1 = {s1.w, nx, ny, nz};
                __builtin_nontemporal_store(o1, &dst4[1 + g1]);
            }
        }
    }

    // edges: new_centers floats 0,1,2 and the final float
    if (blockIdx.x == 0 && threadIdx.x == 0) {
        dst[1] = src[0];
        dst[2] = src[1];
        dst[3] = src[2];
        dst[NFLOAT] = src[NFLOAT - 1];
    }
}

// Rewrite touched rows; per-wave loss partial -> ws (unconditional store).
__global__ void __launch_bounds__(256) update_rows_kernel(
        const float* __restrict__ batch,
        const float* __restrict__ centers,
        const int* __restrict__ head,
        const int* __restrict__ nxt,
        float* __restrict__ out,
        float* __restrict__ loss_part) {
    const int lane = threadIdx.x & 63;
    const int wid  = threadIdx.x >> 6;
    const int gw   = blockIdx.x * 4 + wid;
    const int nw   = gridDim.x * 4;

    float lacc = 0.f;
    for (int r = gw; r < NUM_CLASSES; r += nw) {
        int s = head[r];                       // wave-uniform
        if (s < 0) continue;

        const float* crow = centers + (size_t)r * EMBED;
        float c[8], a[8];
        #pragma unroll
        for (int k = 0; k < 8; ++k) { c[k] = crow[lane + 64 * k]; a[k] = 0.f; }

        while (s >= 0) {
            const float* brow = batch + (size_t)s * EMBED;
            #pragma unroll
            for (int k = 0; k < 8; ++k) {
                float d = brow[lane + 64 * k] - c[k];
                a[k] += d;
                lacc += d * d;
            }
            s = nxt[s];
        }

        float* orow = out + 1 + (size_t)r * EMBED;
        #pragma unroll
        for (int k = 0; k < 8; ++k) orow[lane + 64 * k] = c[k] + ALPHA * a[k];
    }

    #pragma unroll
    for (int off = 32; off > 0; off >>= 1) lacc += __shfl_xor(lacc, off, 64);
    if (lane == 0) loss_part[gw] = lacc;
}

// Sum 4096 partials -> out[0]. One block of 1024.
__global__ void __launch_bounds__(1024) reduce_loss_kernel(
        const float* __restrict__ loss_part, float* __restrict__ out) {
    const int t = threadIdx.x;
    float v = loss_part[t] + loss_part[t + 1024] +
              loss_part[t + 2048] + loss_part[t + 3072];
    #pragma unroll
    for (int off = 32; off > 0; off >>= 1) v += __shfl_xor(v, off, 64);

    __shared__ float wsum[16];
    const int lane = t & 63, wid = t >> 6;
    if (lane == 0) wsum[wid] = v;
    __syncthreads();
    if (t == 0) {
        float s = 0.f;
        #pragma unroll
        for (int i = 0; i < 16; ++i) s += wsum[i];
        out[0] = s * (LAMBDA / (float)BATCH);
    }
}

// ---- fallback (ws too small): blit + per-sample atomics ----
__global__ void center_update_fallback(const int* __restrict__ y,
                                       const float4* __restrict__ batch,
                                       const float4* __restrict__ centers,
                                       float* __restrict__ out) {
    const int b = blockIdx.x, t = threadIdx.x;
    const int cls = y[b];
    const float4 xb = batch[(size_t)b * (EMBED / 4) + t];
    const float4 c  = centers[(size_t)cls * (EMBED / 4) + t];
    const float dx = xb.x - c.x, dy = xb.y - c.y, dz = xb.z - c.z, dw = xb.w - c.w;
    float* orow = out + 1 + (size_t)cls * EMBED + (size_t)t * 4;
    atomicAdd(orow + 0, ALPHA * dx);
    atomicAdd(orow + 1, ALPHA * dy);
    atomicAdd(orow + 2, ALPHA * dz);
    atomicAdd(orow + 3, ALPHA * dw);
    float s = dx * dx + dy * dy + dz * dz + dw * dw;
    #pragma unroll
    for (int off = 32; off > 0; off >>= 1) s += __shfl_down(s, off, 64);
    __shared__ float wsum[2];
    const int lane = t & 63, wid = t >> 6;
    if (lane == 0) wsum[wid] = s;
    __syncthreads();
    if (t == 0) atomicAdd(out, (wsum[0] + wsum[1]) * (LAMBDA / (float)BATCH));
}

extern "C" void kernel_launch(void* const* d_in, const int* in_sizes, int n_in,
                              void* d_out, int out_size, void* d_ws, size_t ws_size,
                              hipStream_t stream) {
    const int*   y       = (const int*)d_in[0];
    const float* batch   = (const float*)d_in[1];
    const float* centers = (const float*)d_in[2];
    float*       out     = (float*)d_out;

    const size_t head_bytes = (size_t)NUM_CLASSES * sizeof(int);
    const size_t next_bytes = (size_t)BATCH * sizeof(int);
    const size_t loss_bytes = (size_t)NWAVES_UPD * sizeof(float);

    if (ws_size >= head_bytes + next_bytes + loss_bytes) {
        int*   head      = (int*)d_ws;
        int*   nxt       = (int*)((char*)d_ws + head_bytes);
        float* loss_part = (float*)((char*)d_ws + head_bytes + next_bytes);

        init_head_kernel<<<(NUM_CLASSES + 1023) / 1024, 1024, 0, stream>>>(head);
        link_kernel<<<(BATCH + 255) / 256, 256, 0, stream>>>(y, head, nxt);
        copy_shift2_kernel<<<2048, 256, 0, stream>>>(
            (const f4*)centers, (f4*)out, centers, out);
        update_rows_kernel<<<1024, 256, 0, stream>>>(batch, centers, head, nxt,
                                                     out, loss_part);
        reduce_loss_kernel<<<1, 1024, 0, stream>>>(loss_part, out);
    } else {
        (void)hipMemsetAsync(out, 0, sizeof(float), stream);
        (void)hipMemcpyAsync(out + 1, centers, NFLOAT * sizeof(float),
                             hipMemcpyDeviceToDevice, stream);
        center_update_fallback<<<BATCH, EMBED / 4, 0, stream>>>(
            y, (const float4*)batch, (const float4*)centers, out);
    }
}

// Round 12
// 87.126 us; speedup vs baseline: 1.4189x; 1.4189x over previous
//
#include <hip/hip_runtime.h>

// CenterLossForward:
//   loss        = LAMBDA/BATCH * sum_b ||batch_b - centers[y_b]||^2
//   new_centers = centers; new_centers[y_b] += ALPHA*(batch_b - centers[y_b])  (dups accumulate)
// d_out layout: [loss (1 float)] [new_centers (NUM_CLASSES*EMBED floats)]
//
// R12 = best-of: R6's copy (plain f4 loads + shfl realign + lane-contiguous
// NT stores — every variant tried converged to <=2.9 TB/s HBM-side on d_out;
// strided stores (R11) caused partial-line writebacks, WRITE 206->326 MB) +
// R11's fill-free graph (own init, per-wave loss partials, final reduce).

constexpr int   NUM_CLASSES = 100000;
constexpr int   EMBED       = 512;
constexpr int   BATCH       = 4096;
constexpr float LAMBDA      = 0.01f;
constexpr float ALPHA       = 0.1f;

constexpr long  NFLOAT = (long)NUM_CLASSES * EMBED;   // 51,200,000
constexpr long  NGRP   = (NFLOAT - 3) / 4;            // 12,799,999 dst float4 groups
constexpr long  NSRC4  = NFLOAT / 4;                  // 12,800,000 src float4 words
constexpr int   NWAVES_UPD = 4096;                    // update grid: 1024 blk * 4 waves

typedef float f4 __attribute__((ext_vector_type(4)));

__global__ void init_head_kernel(int* __restrict__ head) {
    int c = blockIdx.x * blockDim.x + threadIdx.x;
    if (c < NUM_CLASSES) head[c] = -1;
}

__global__ void link_kernel(const int* __restrict__ y, int* __restrict__ head,
                            int* __restrict__ nxt) {
    int s = blockIdx.x * blockDim.x + threadIdx.x;
    if (s < BATCH) nxt[s] = atomicExch(&head[y[s]], s);
}

// R6 copy: dst4[1+g] = {src[4g+3] .. src[4g+6]}; aligned f4 load, shfl-down
// realign, lane-contiguous aligned f4 NT store.
__global__ void __launch_bounds__(256) copy_shift_kernel(
        const f4* __restrict__ src4, f4* __restrict__ dst4,
        const float* __restrict__ src, float* __restrict__ dst) {
    const int  lane = threadIdx.x & 63;
    const long gw   = (long)((blockIdx.x * blockDim.x + threadIdx.x) >> 6);
    const long nw   = (long)((gridDim.x * blockDim.x) >> 6);

    for (long base = gw * 64; base < NGRP; base += nw * 64) {
        const long g  = base + lane;
        f4 v = (g < NSRC4) ? src4[g] : (f4){0.f, 0.f, 0.f, 0.f};

        f4 vn;
        vn.x = __shfl_down(v.x, 1, 64);
        vn.y = __shfl_down(v.y, 1, 64);
        vn.z = __shfl_down(v.z, 1, 64);
        vn.w = __shfl_down(v.w, 1, 64);
        if (lane == 63 && g + 1 < NSRC4) vn = src4[g + 1];

        if (g < NGRP) {
            f4 o = {v.w, vn.x, vn.y, vn.z};
            __builtin_nontemporal_store(o, &dst4[1 + g]);
        }
    }

    // edges: new_centers floats 0,1,2 and the final float
    if (blockIdx.x == 0 && threadIdx.x == 0) {
        dst[1] = src[0];
        dst[2] = src[1];
        dst[3] = src[2];
        dst[NFLOAT] = src[NFLOAT - 1];
    }
}

// Rewrite touched rows; per-wave loss partial -> ws (unconditional store).
__global__ void __launch_bounds__(256) update_rows_kernel(
        const float* __restrict__ batch,
        const float* __restrict__ centers,
        const int* __restrict__ head,
        const int* __restrict__ nxt,
        float* __restrict__ out,
        float* __restrict__ loss_part) {
    const int lane = threadIdx.x & 63;
    const int wid  = threadIdx.x >> 6;
    const int gw   = blockIdx.x * 4 + wid;
    const int nw   = gridDim.x * 4;

    float lacc = 0.f;
    for (int r = gw; r < NUM_CLASSES; r += nw) {
        int s = head[r];                       // wave-uniform
        if (s < 0) continue;

        const float* crow = centers + (size_t)r * EMBED;
        float c[8], a[8];
        #pragma unroll
        for (int k = 0; k < 8; ++k) { c[k] = crow[lane + 64 * k]; a[k] = 0.f; }

        while (s >= 0) {
            const float* brow = batch + (size_t)s * EMBED;
            #pragma unroll
            for (int k = 0; k < 8; ++k) {
                float d = brow[lane + 64 * k] - c[k];
                a[k] += d;
                lacc += d * d;
            }
            s = nxt[s];
        }

        float* orow = out + 1 + (size_t)r * EMBED;
        #pragma unroll
        for (int k = 0; k < 8; ++k) orow[lane + 64 * k] = c[k] + ALPHA * a[k];
    }

    #pragma unroll
    for (int off = 32; off > 0; off >>= 1) lacc += __shfl_xor(lacc, off, 64);
    if (lane == 0) loss_part[gw] = lacc;
}

// Sum 4096 partials -> out[0]. One block of 1024.
__global__ void __launch_bounds__(1024) reduce_loss_kernel(
        const float* __restrict__ loss_part, float* __restrict__ out) {
    const int t = threadIdx.x;
    float v = loss_part[t] + loss_part[t + 1024] +
              loss_part[t + 2048] + loss_part[t + 3072];
    #pragma unroll
    for (int off = 32; off > 0; off >>= 1) v += __shfl_xor(v, off, 64);

    __shared__ float wsum[16];
    const int lane = t & 63, wid = t >> 6;
    if (lane == 0) wsum[wid] = v;
    __syncthreads();
    if (t == 0) {
        float s = 0.f;
        #pragma unroll
        for (int i = 0; i < 16; ++i) s += wsum[i];
        out[0] = s * (LAMBDA / (float)BATCH);
    }
}

// ---- fallback (ws too small): blit + per-sample atomics ----
__global__ void center_update_fallback(const int* __restrict__ y,
                                       const float4* __restrict__ batch,
                                       const float4* __restrict__ centers,
                                       float* __restrict__ out) {
    const int b = blockIdx.x, t = threadIdx.x;
    const int cls = y[b];
    const float4 xb = batch[(size_t)b * (EMBED / 4) + t];
    const float4 c  = centers[(size_t)cls * (EMBED / 4) + t];
    const float dx = xb.x - c.x, dy = xb.y - c.y, dz = xb.z - c.z, dw = xb.w - c.w;
    float* orow = out + 1 + (size_t)cls * EMBED + (size_t)t * 4;
    atomicAdd(orow + 0, ALPHA * dx);
    atomicAdd(orow + 1, ALPHA * dy);
    atomicAdd(orow + 2, ALPHA * dz);
    atomicAdd(orow + 3, ALPHA * dw);
    float s = dx * dx + dy * dy + dz * dz + dw * dw;
    #pragma unroll
    for (int off = 32; off > 0; off >>= 1) s += __shfl_down(s, off, 64);
    __shared__ float wsum[2];
    const int lane = t & 63, wid = t >> 6;
    if (lane == 0) wsum[wid] = s;
    __syncthreads();
    if (t == 0) atomicAdd(out, (wsum[0] + wsum[1]) * (LAMBDA / (float)BATCH));
}

extern "C" void kernel_launch(void* const* d_in, const int* in_sizes, int n_in,
                              void* d_out, int out_size, void* d_ws, size_t ws_size,
                              hipStream_t stream) {
    const int*   y       = (const int*)d_in[0];
    const float* batch   = (const float*)d_in[1];
    const float* centers = (const float*)d_in[2];
    float*       out     = (float*)d_out;

    const size_t head_bytes = (size_t)NUM_CLASSES * sizeof(int);
    const size_t next_bytes = (size_t)BATCH * sizeof(int);
    const size_t loss_bytes = (size_t)NWAVES_UPD * sizeof(float);

    if (ws_size >= head_bytes + next_bytes + loss_bytes) {
        int*   head      = (int*)d_ws;
        int*   nxt       = (int*)((char*)d_ws + head_bytes);
        float* loss_part = (float*)((char*)d_ws + head_bytes + next_bytes);

        init_head_kernel<<<(NUM_CLASSES + 1023) / 1024, 1024, 0, stream>>>(head);
        link_kernel<<<(BATCH + 255) / 256, 256, 0, stream>>>(y, head, nxt);
        copy_shift_kernel<<<2048, 256, 0, stream>>>(
            (const f4*)centers, (f4*)out, centers, out);
        update_rows_kernel<<<1024, 256, 0, stream>>>(batch, centers, head, nxt,
                                                     out, loss_part);
        reduce_loss_kernel<<<1, 1024, 0, stream>>>(loss_part, out);
    } else {
        (void)hipMemsetAsync(out, 0, sizeof(float), stream);
        (void)hipMemcpyAsync(out + 1, centers, NFLOAT * sizeof(float),
                             hipMemcpyDeviceToDevice, stream);
        center_update_fallback<<<BATCH, EMBED / 4, 0, stream>>>(
            y, (const float4*)batch, (const float4*)centers, out);
    }
}

// Round 13
// 79.620 us; speedup vs baseline: 1.5526x; 1.0943x over previous
//
#include <hip/hip_runtime.h>

// CenterLossForward:
//   loss        = LAMBDA/BATCH * sum_b ||batch_b - centers[y_b]||^2
//   new_centers = centers; new_centers[y_b] += ALPHA*(batch_b - centers[y_b])  (dups accumulate)
// d_out layout: [loss (1 float)] [new_centers (NUM_CLASSES*EMBED floats)]
//
// R13: single fused row pass. Per wave: one row (512 floats = 2 f4/lane),
// optional list-walk update for touched rows, shfl-realign (+1 float shift),
// lane-contiguous NT f4 stores + 4 scalar edge floats (lanes 0/63; edge
// dwords share cache lines with neighbor rows' stores -> L2 merge).
// Eliminates R12's separate update pass (double write + centers re-read).

constexpr int   NUM_CLASSES = 100000;
constexpr int   EMBED       = 512;
constexpr int   BATCH       = 4096;
constexpr float LAMBDA      = 0.01f;
constexpr float ALPHA       = 0.1f;

constexpr long  NFLOAT = (long)NUM_CLASSES * EMBED;   // 51,200,000
constexpr int   NWAVES = 8192;                        // 2048 blocks * 4 waves

typedef float f4 __attribute__((ext_vector_type(4)));

__global__ void init_head_kernel(int* __restrict__ head) {
    int c = blockIdx.x * blockDim.x + threadIdx.x;
    if (c < NUM_CLASSES) head[c] = -1;
}

__global__ void link_kernel(const int* __restrict__ y, int* __restrict__ head,
                            int* __restrict__ nxt) {
    int s = blockIdx.x * blockDim.x + threadIdx.x;
    if (s < BATCH) nxt[s] = atomicExch(&head[y[s]], s);
}

// One wave per row r. Row floats: src[512r .. 512r+511].
// Output dst floats: [1+512r .. 512r+512].
//   lane 0 scalars: dst[1+512r..3+512r] = {c0.x, c0.y, c0.z}
//   f4 group j (=i*64+lane, j<127): dst4[128r+1+j] = {v_j.w, v_{j+1}.xyz}
//   lane 63 scalar: dst[512r+512] = c1.w
__global__ void __launch_bounds__(256) fused_rows_kernel(
        const f4* __restrict__ src4,
        const f4* __restrict__ batch4,
        f4* __restrict__ dst4,
        const float* __restrict__ src,
        float* __restrict__ dst,
        const int* __restrict__ head,
        const int* __restrict__ nxt,
        float* __restrict__ loss_part) {
    const int lane = threadIdx.x & 63;
    const int wid  = threadIdx.x >> 6;
    const int gw   = blockIdx.x * 4 + wid;
    const int nw   = gridDim.x * 4;

    float lacc = 0.f;
    for (int r = gw; r < NUM_CLASSES; r += nw) {
        const long base = 128L * r;
        f4 c0 = src4[base + lane];
        f4 c1 = src4[base + 64 + lane];

        int s = head[r];                       // wave-uniform
        if (s >= 0) {
            f4 a0 = {0.f, 0.f, 0.f, 0.f}, a1 = a0;
            do {
                const long bb = 128L * s;
                f4 b0 = batch4[bb + lane];
                f4 b1 = batch4[bb + 64 + lane];
                f4 d0 = b0 - c0;
                f4 d1 = b1 - c1;
                a0 += d0;
                a1 += d1;
                lacc += d0.x * d0.x + d0.y * d0.y + d0.z * d0.z + d0.w * d0.w
                      + d1.x * d1.x + d1.y * d1.y + d1.z * d1.z + d1.w * d1.w;
                s = nxt[s];
            } while (s >= 0);
            c0 += ALPHA * a0;
            c1 += ALPHA * a1;
        }

        // realign: group j needs v_{j+1}.xyz (next lane; i=0 lane63 -> lane0's c1)
        float c1x0 = __shfl(c1.x, 0, 64);
        float c1y0 = __shfl(c1.y, 0, 64);
        float c1z0 = __shfl(c1.z, 0, 64);
        float n0x = __shfl_down(c0.x, 1, 64);
        float n0y = __shfl_down(c0.y, 1, 64);
        float n0z = __shfl_down(c0.z, 1, 64);
        float n1x = __shfl_down(c1.x, 1, 64);
        float n1y = __shfl_down(c1.y, 1, 64);
        float n1z = __shfl_down(c1.z, 1, 64);
        if (lane == 63) { n0x = c1x0; n0y = c1y0; n0z = c1z0; }

        f4 o0 = {c0.w, n0x, n0y, n0z};
        __builtin_nontemporal_store(o0, &dst4[base + 1 + lane]);
        if (lane < 63) {
            f4 o1 = {c1.w, n1x, n1y, n1z};
            __builtin_nontemporal_store(o1, &dst4[base + 65 + lane]);
        }
        if (lane == 0) {
            dst[1 + 512L * r] = c0.x;
            dst[2 + 512L * r] = c0.y;
            dst[3 + 512L * r] = c0.z;
        }
        if (lane == 63) {
            dst[512L * r + 512] = c1.w;
        }
    }

    #pragma unroll
    for (int off = 32; off > 0; off >>= 1) lacc += __shfl_xor(lacc, off, 64);
    if (lane == 0) loss_part[gw] = lacc;
}

// Sum NWAVES partials -> out[0]. One block of 1024.
__global__ void __launch_bounds__(1024) reduce_loss_kernel(
        const float* __restrict__ loss_part, float* __restrict__ out) {
    const int t = threadIdx.x;
    float v = 0.f;
    #pragma unroll
    for (int k = 0; k < NWAVES / 1024; ++k) v += loss_part[t + k * 1024];
    #pragma unroll
    for (int off = 32; off > 0; off >>= 1) v += __shfl_xor(v, off, 64);

    __shared__ float wsum[16];
    const int lane = t & 63, wid = t >> 6;
    if (lane == 0) wsum[wid] = v;
    __syncthreads();
    if (t == 0) {
        float s = 0.f;
        #pragma unroll
        for (int i = 0; i < 16; ++i) s += wsum[i];
        out[0] = s * (LAMBDA / (float)BATCH);
    }
}

// ---- fallback (ws too small): blit + per-sample atomics ----
__global__ void center_update_fallback(const int* __restrict__ y,
                                       const float4* __restrict__ batch,
                                       const float4* __restrict__ centers,
                                       float* __restrict__ out) {
    const int b = blockIdx.x, t = threadIdx.x;
    const int cls = y[b];
    const float4 xb = batch[(size_t)b * (EMBED / 4) + t];
    const float4 c  = centers[(size_t)cls * (EMBED / 4) + t];
    const float dx = xb.x - c.x, dy = xb.y - c.y, dz = xb.z - c.z, dw = xb.w - c.w;
    float* orow = out + 1 + (size_t)cls * EMBED + (size_t)t * 4;
    atomicAdd(orow + 0, ALPHA * dx);
    atomicAdd(orow + 1, ALPHA * dy);
    atomicAdd(orow + 2, ALPHA * dz);
    atomicAdd(orow + 3, ALPHA * dw);
    float s = dx * dx + dy * dy + dz * dz + dw * dw;
    #pragma unroll
    for (int off = 32; off > 0; off >>= 1) s += __shfl_down(s, off, 64);
    __shared__ float wsum[2];
    const int lane = t & 63, wid = t >> 6;
    if (lane == 0) wsum[wid] = s;
    __syncthreads();
    if (t == 0) atomicAdd(out, (wsum[0] + wsum[1]) * (LAMBDA / (float)BATCH));
}

extern "C" void kernel_launch(void* const* d_in, const int* in_sizes, int n_in,
                              void* d_out, int out_size, void* d_ws, size_t ws_size,
                              hipStream_t stream) {
    const int*   y       = (const int*)d_in[0];
    const float* batch   = (const float*)d_in[1];
    const float* centers = (const float*)d_in[2];
    float*       out     = (float*)d_out;

    const size_t head_bytes = (size_t)NUM_CLASSES * sizeof(int);
    const size_t next_bytes = (size_t)BATCH * sizeof(int);
    const size_t loss_bytes = (size_t)NWAVES * sizeof(float);

    if (ws_size >= head_bytes + next_bytes + loss_bytes) {
        int*   head      = (int*)d_ws;
        int*   nxt       = (int*)((char*)d_ws + head_bytes);
        float* loss_part = (float*)((char*)d_ws + head_bytes + next_bytes);

        init_head_kernel<<<(NUM_CLASSES + 1023) / 1024, 1024, 0, stream>>>(head);
        link_kernel<<<(BATCH + 255) / 256, 256, 0, stream>>>(y, head, nxt);
        fused_rows_kernel<<<2048, 256, 0, stream>>>(
            (const f4*)centers, (const f4*)batch, (f4*)out,
            centers, out, head, nxt, loss_part);
        reduce_loss_kernel<<<1, 1024, 0, stream>>>(loss_part, out);
    } else {
        (void)hipMemsetAsync(out, 0, sizeof(float), stream);
        (void)hipMemcpyAsync(out + 1, centers, NFLOAT * sizeof(float),
                             hipMemcpyDeviceToDevice, stream);
        center_update_fallback<<<BATCH, EMBED / 4, 0, stream>>>(
            y, (const float4*)batch, (const float4*)centers, out);
    }
}